// Round 1
// 1341.354 us; speedup vs baseline: 1.4214x; 1.4214x over previous
//
#include <hip/hip_runtime.h>
#include <hip/hip_bf16.h>
#include <stdint.h>

typedef __bf16 bf16_t;
typedef __bf16 bf16x8 __attribute__((ext_vector_type(8)));
typedef __bf16 bf16x4_t __attribute__((ext_vector_type(4)));
typedef float f32x4 __attribute__((ext_vector_type(4)));

#define T_STEPS 512
#define B_SZ 64
#define I_SZ 512
#define H_SZ 512
#define NB 4            // batch groups (16 rows each)
#define BS 16
#define NC 32           // column-group WGs per batch group (16 h-cols each)
#define CS 16

// ws layout (bytes)
#define XBF_OFF   0ull                     // 32 MB: x bf16, consumer-fragment order
#define WBF_OFF   33554432ull              // 4 MB: W_all bf16 row-major [2048][1024]
#define BALL_OFF  (WBF_OFF + 4194304ull)   // 8 KB: b_all f32
#define HEXP_OFF  (BALL_OFF + 8192ull)     // 256 KB: packed h exchange
// HEXP: [par 2][bg 4][wave-half 2][kt 8][lane 64][j 8] dwords, each = (tag<<16)|bf16(h)

__device__ __forceinline__ float sigmoid_fast(float x) {
  return 1.f / (1.f + __expf(-x));
}
__device__ __forceinline__ float tanh_fast(float x) {
  float xc = fminf(fmaxf(x, -10.f), 10.f);
  float e = __expf(2.f * xc);
  return (e - 1.f) / (e + 1.f);
}

// ---- device-coherent (L1+L2 bypass -> Infinity Cache) accessors (R2-proven instrs) ----
__device__ __forceinline__ uint4 load_b128_cc(const void* addr) {
  uint4 v;
  asm volatile("global_load_dwordx4 %0, %1, off sc0 sc1"
               : "=v"(v) : "v"(addr) : "memory");
  return v;
}
__device__ __forceinline__ void store_b32_cc(void* addr, uint32_t v) {
  asm volatile("global_store_dword %0, %1, off sc0 sc1"
               :: "v"(addr), "v"(v) : "memory");
}
__device__ __forceinline__ void wait_vm0() {
  asm volatile("s_waitcnt vmcnt(0)" ::: "memory");
}

// ---------- prep: cast x to bf16 in consumer-fragment order ----------
// element linear chunk c (8 bf16 / 16B): c = t*4096 + bg*1024 + w*512 + kt*64 + lane
// source: row = bg*16 + (lane&15), col = w*256 + kt*32 + (lane>>4)*8
__global__ void prep_x(const float* __restrict__ x, bf16_t* __restrict__ xbf) {
  const int nch = (T_STEPS * B_SZ * I_SZ) / 8;   // 2,097,152
  int c = blockIdx.x * blockDim.x + threadIdx.x;
  int stride = gridDim.x * blockDim.x;
  for (; c < nch; c += stride) {
    int lane = c & 63;
    int kt = (c >> 6) & 7;
    int w  = (c >> 9) & 1;
    int bg = (c >> 10) & 3;
    int t  = c >> 12;
    int r = lane & 15, quad = lane >> 4;
    const float* src = x + ((size_t)t * B_SZ + bg * BS + r) * I_SZ + w * 256 + kt * 32 + quad * 8;
    float4 lo = *(const float4*)src;
    float4 hi = *(const float4*)(src + 4);
    bf16x8 o = { (bf16_t)lo.x, (bf16_t)lo.y, (bf16_t)lo.z, (bf16_t)lo.w,
                 (bf16_t)hi.x, (bf16_t)hi.y, (bf16_t)hi.z, (bf16_t)hi.w };
    *(bf16x8*)(xbf + (size_t)c * 8) = o;
  }
}

// ---------- prep: W_all bf16, b_all f32, zero packed h-exchange ----------
__global__ void prep_rest(const float* __restrict__ wf, const float* __restrict__ wi,
                          const float* __restrict__ wgm, const float* __restrict__ wo,
                          const float* __restrict__ bfv, const float* __restrict__ biv,
                          const float* __restrict__ bgv, const float* __restrict__ bov,
                          bf16_t* __restrict__ wbf, float* __restrict__ ball,
                          uint32_t* __restrict__ hexp) {
  int gtid = blockIdx.x * blockDim.x + threadIdx.x;
  int stride = gridDim.x * blockDim.x;
  const int WCH = (2048 * 1024) / 4;  // 524288 float4 chunks
  for (int i = gtid; i < WCH; i += stride) {
    int r = i >> 8;               // W_all row (0..2047)
    int c = (i & 255) << 2;       // col base
    int g = r >> 9, sr = r & 511;
    const float* src = (g == 0) ? wf : (g == 1) ? wi : (g == 2) ? wgm : wo;
    float4 v = *(const float4*)(src + (size_t)sr * 1024 + c);
    bf16x4_t o = { (bf16_t)v.x, (bf16_t)v.y, (bf16_t)v.z, (bf16_t)v.w };
    *(bf16x4_t*)(wbf + (size_t)r * 1024 + c) = o;
  }
  for (int i = gtid; i < 2048; i += stride) {
    int g = i >> 9;
    const float* src = (g == 0) ? bfv : (g == 1) ? biv : (g == 2) ? bgv : bov;
    ball[i] = src[i & 511];
  }
  for (int i = gtid; i < 65536; i += stride) hexp[i] = 0;  // tag 0 == "h(-1)=0 ready"
}

// ---------- main recurrent kernel: 128 WGs, tag-in-payload single-round-trip sync ----------
__global__ __launch_bounds__(256, 1) void qlstm_main(
    const bf16_t* __restrict__ xbf, const bf16_t* __restrict__ wbf,
    const float* __restrict__ ball, uint32_t* __restrict__ hexp,
    float* __restrict__ out) {
  const int wg = blockIdx.x;
  const int bg = wg >> 5;      // batch group 0..3
  const int ic = wg & 31;      // column group 0..31
  const int tid = threadIdx.x;
  const int wave = tid >> 6;   // K-quarter owner: 0,1 = x halves; 2,3 = h halves
  const int lane = tid & 63;
  const int l15 = lane & 15;
  const int quad = lane >> 4;

  // partial-sum exchange: [par][wave][row 16][col 64(+4 pad)] (col = l15*4 + gate)
  __shared__ __align__(16) float Gp[2][4][16][68];

  // Register-resident B fragments: W_all row = g*512 + ic*16 + l15,
  // k = wave*256 + kt*32 + quad*8  (same MFMA operand convention as the passing kernel)
  bf16x8 wfr[4][8];
#pragma unroll
  for (int g = 0; g < 4; ++g) {
    const bf16_t* wp = wbf + ((size_t)(g * 512 + ic * CS + l15)) * 1024 + wave * 256 + quad * 8;
#pragma unroll
    for (int kt = 0; kt < 8; ++kt) wfr[g][kt] = *(const bf16x8*)(wp + kt * 32);
  }

  const int erow = tid >> 4;
  const int ecol = tid & 15;
  const float bias_f = ball[0 * 512 + ic * CS + ecol];
  const float bias_i = ball[1 * 512 + ic * CS + ecol];
  const float bias_g = ball[2 * 512 + ic * CS + ecol];
  const float bias_o = ball[3 * 512 + ic * CS + ecol];

  const int brow = bg * BS + erow;
  const int hcol = ic * CS + ecol;

  // producer dest (const part): fragment position of (erow, hcol) in consumer layout
  const int wh = hcol >> 8;            // which consumer wave-half
  const int kp = hcol & 255;           // k within half
  const int pof = wh * 4096 + ((kp >> 5) << 9) + ((((kp >> 3) & 3) * 16 + erow) << 3) + (kp & 7);
  // consumer base (waves 2,3 only)
  const int cof = ((wave - 2) << 12) + (lane << 3);

  float c_state = 0.f, h = 0.f;
  const size_t out_hx = (size_t)T_STEPS * B_SZ * H_SZ;

  // x fragment base (waves 0,1): full offset = t*32768 + (bg*2+wave)*4096 + kt*512 + lane*8
  const bf16_t* xw0 = xbf + ((size_t)(bg * 2 + wave) << 12) + lane * 8;

#pragma unroll 1
  for (int t = 0; t < T_STEPS; ++t) {
    const int par = t & 1;

    bf16x8 f[8];
    if (wave < 2) {
      // ---- x K-quarter: direct fragment loads (L3-resident), no LDS
      const bf16_t* xp = xw0 + ((size_t)t << 15);
#pragma unroll
      for (int kt = 0; kt < 8; ++kt) f[kt] = *(const bf16x8*)(xp + kt * 512);
    } else {
      // ---- h K-quarter: poll packed (tag|h) dwords until all tags == t
      const uint32_t* hp = hexp + ((size_t)(((par ^ 1) * 4 + bg) << 13)) + cof;
      uint4 v[16];
      const uint32_t pat = (uint32_t)t << 16;
      for (;;) {
#pragma unroll
        for (int kt = 0; kt < 8; ++kt) {
          v[2 * kt]     = load_b128_cc(hp + kt * 512);
          v[2 * kt + 1] = load_b128_cc(hp + kt * 512 + 4);
        }
        wait_vm0();
        uint32_t bad = 0;
#pragma unroll
        for (int q = 0; q < 16; ++q)
          bad |= (v[q].x ^ pat) | (v[q].y ^ pat) | (v[q].z ^ pat) | (v[q].w ^ pat);
        if (__all((int)((bad & 0xffff0000u) == 0))) break;
        __builtin_amdgcn_s_sleep(1);
      }
      // unpack low-16 halves -> bf16x8 fragments (lane-local, no LDS)
#pragma unroll
      for (int kt = 0; kt < 8; ++kt) {
        uint4 a = v[2 * kt], b = v[2 * kt + 1];
        union { uint32_t u[4]; bf16x8 fv; } cv;
        cv.u[0] = (a.x & 0xffffu) | (a.y << 16);
        cv.u[1] = (a.z & 0xffffu) | (a.w << 16);
        cv.u[2] = (b.x & 0xffffu) | (b.y << 16);
        cv.u[3] = (b.z & 0xffffu) | (b.w << 16);
        f[kt] = cv.fv;
      }
    }

    // ---- K-quarter GEMM: 4 gates (independent chains), K=256
    f32x4 a0 = {0, 0, 0, 0}, a1 = {0, 0, 0, 0}, a2 = {0, 0, 0, 0}, a3 = {0, 0, 0, 0};
#pragma unroll
    for (int kt = 0; kt < 8; ++kt) {
      a0 = __builtin_amdgcn_mfma_f32_16x16x32_bf16(f[kt], wfr[0][kt], a0, 0, 0, 0);
      a1 = __builtin_amdgcn_mfma_f32_16x16x32_bf16(f[kt], wfr[1][kt], a1, 0, 0, 0);
      a2 = __builtin_amdgcn_mfma_f32_16x16x32_bf16(f[kt], wfr[2][kt], a2, 0, 0, 0);
      a3 = __builtin_amdgcn_mfma_f32_16x16x32_bf16(f[kt], wfr[3][kt], a3, 0, 0, 0);
    }

    // ---- cross-wave K reduction via LDS (one barrier per step, parity-double-buffered)
    // C/D layout: col = l15, row = quad*4 + i
#pragma unroll
    for (int i = 0; i < 4; ++i) {
      f32x4 pv = { a0[i], a1[i], a2[i], a3[i] };
      *(f32x4*)&Gp[par][wave][quad * 4 + i][l15 * 4] = pv;
    }
    __syncthreads();

    f32x4 s = *(const f32x4*)&Gp[par][0][erow][ecol * 4];
    s += *(const f32x4*)&Gp[par][1][erow][ecol * 4];
    s += *(const f32x4*)&Gp[par][2][erow][ecol * 4];
    s += *(const f32x4*)&Gp[par][3][erow][ecol * 4];

    // ---- LSTM cell (fp32), per-thread c state
    float fg = sigmoid_fast(s[0] + bias_f);
    float ig = sigmoid_fast(s[1] + bias_i);
    float gg = tanh_fast(s[2] + bias_g);
    float og = sigmoid_fast(s[3] + bias_o);
    c_state = fg * c_state + ig * gg;
    h = og * tanh_fast(c_state);

    // ---- publish: single dword (tag t+1 | bf16 h) — tag rides with payload, no drain/flag
    union { bf16_t b; unsigned short u; } cvt;
    cvt.b = (bf16_t)h;
    uint32_t pk = ((uint32_t)(t + 1) << 16) | (uint32_t)cvt.u;
    store_b32_cc(hexp + (((par * 4 + bg) << 13) + pof), pk);

    // ---- out store (off critical path)
    out[((size_t)t * B_SZ + brow) * H_SZ + hcol] = h;
  }

  out[out_hx + (size_t)brow * H_SZ + hcol] = h;
  out[out_hx + (size_t)(B_SZ * H_SZ) + (size_t)brow * H_SZ + hcol] = c_state;
}

extern "C" void kernel_launch(void* const* d_in, const int* in_sizes, int n_in,
                              void* d_out, int out_size, void* d_ws, size_t ws_size,
                              hipStream_t stream) {
  const float* x   = (const float*)d_in[0];
  const float* Wf  = (const float*)d_in[1];
  const float* bfv = (const float*)d_in[2];
  const float* Wi  = (const float*)d_in[3];
  const float* biv = (const float*)d_in[4];
  const float* Wg  = (const float*)d_in[5];
  const float* bgv = (const float*)d_in[6];
  const float* Wo  = (const float*)d_in[7];
  const float* bov = (const float*)d_in[8];
  float* out = (float*)d_out;

  char* ws = (char*)d_ws;
  bf16_t* xbf    = (bf16_t*)(ws + XBF_OFF);
  bf16_t* wbf    = (bf16_t*)(ws + WBF_OFF);
  float*  ball   = (float*)(ws + BALL_OFF);
  uint32_t* hexp = (uint32_t*)(ws + HEXP_OFF);

  prep_x<<<dim3(2048), dim3(256), 0, stream>>>(x, xbf);
  prep_rest<<<dim3(1024), dim3(256), 0, stream>>>(Wf, Wi, Wg, Wo, bfv, biv, bgv, bov,
                                                  wbf, ball, hexp);
  qlstm_main<<<dim3(NB * NC), dim3(256), 0, stream>>>(xbf, wbf, ball, hexp, out);
}